// Round 3
// baseline (250.171 us; speedup 1.0000x reference)
//
#include <hip/hip_runtime.h>
#include <stdint.h>
#include <stddef.h>

typedef unsigned short u16;
typedef unsigned int   u32;
typedef __bf16  bf16x8 __attribute__((ext_vector_type(8)));
typedef unsigned short us8 __attribute__((ext_vector_type(8)));
typedef unsigned short us4 __attribute__((ext_vector_type(4)));
typedef float   f32x4  __attribute__((ext_vector_type(4)));

#define DEVFN static __device__ __forceinline__

DEVFN u16 f2bf(float f) {            // RTNE float->bf16 (no NaN inputs here)
    u32 u = __float_as_uint(f);
    return (u16)((u + 0x7FFFu + ((u >> 16) & 1u)) >> 16);
}
DEVFN float bf2f(u16 h) { return __uint_as_float(((u32)h) << 16); }

// async 16B/lane global->LDS (wave-uniform LDS base, per-lane global addr)
#define GLL(g, l) __builtin_amdgcn_global_load_lds( \
    (__attribute__((address_space(1))) void*)(g),   \
    (__attribute__((address_space(3))) void*)(l), 16, 0, 0)

// ---------------- geometry ----------------
#define NREAL 12544          // 64 * 196 real positions
#define NPAD  16384          // 64 * 256 padded (16x16) positions
#define GUARD_ROWS 32        // guard rows around act1 (conv2 row shifts are +-17)

// ---------------- block reduce max ----------------
DEVFN float blockReduceMax(float m) {
    for (int off = 32; off; off >>= 1) m = fmaxf(m, __shfl_xor(m, off));
    __shared__ float s[4];
    int lane = threadIdx.x & 63, w = threadIdx.x >> 6;
    if (lane == 0) s[w] = m;
    __syncthreads();
    m = fmaxf(fmaxf(s[0], s[1]), fmaxf(s[2], s[3]));
    return m;
}

// ---------------- merged prep kernel ----------------
// bid 0..255    : wq1 (w1 [256][1024] -> w1d [256][2048] dup, sw1)
// bid 256..511  : wq2 (w2 [256][2304] -> w2t [256][2304] k=(r*256+ci), sw2)
// bid 512..1535 : wq3 (w3 [1024][256] -> w3q, sw3)
// bid 1536..2559: split (x NCHW fp32 -> xsplit [12544][2048] bf16 hi|lo)
__global__ __launch_bounds__(256) void k_prep(
    const float* __restrict__ w1, const float* __restrict__ w2, const float* __restrict__ w3,
    const float* __restrict__ x,
    u16* __restrict__ w1d, u16* __restrict__ w2t, u16* __restrict__ w3q,
    float* __restrict__ sw1, float* __restrict__ sw2, float* __restrict__ sw3,
    u16* __restrict__ xsplit)
{
    __shared__ float tile[64*197];
    const int bid = blockIdx.x, t = threadIdx.x;

    if (bid < 256) {                       // ---- wq1
        int p = bid;
        const float* wr = w1 + (size_t)p * 1024;
        float v[4], m = 0.f;
        for (int i = 0; i < 4; ++i) { v[i] = wr[t + i*256]; m = fmaxf(m, fabsf(v[i])); }
        m = blockReduceMax(m);
        float s = fmaxf(m / 127.0f, 1e-8f);
        if (t == 0) sw1[p] = s;
        for (int i = 0; i < 4; ++i) {
            float q = rintf(v[i] / s);
            q = fminf(fmaxf(q, -127.f), 127.f);
            u16 h = f2bf(q);
            w1d[(size_t)p*2048 + t + i*256]        = h;
            w1d[(size_t)p*2048 + 1024 + t + i*256] = h;
        }
    } else if (bid < 512) {                // ---- wq2
        int p = bid - 256;
        const float* wr = w2 + (size_t)p * 2304;
        float v[9], m = 0.f;
        for (int i = 0; i < 9; ++i) { v[i] = wr[t + i*256]; m = fmaxf(m, fabsf(v[i])); }
        m = blockReduceMax(m);
        float s = fmaxf(m / 127.0f, 1e-8f);
        if (t == 0) sw2[p] = s;
        for (int i = 0; i < 9; ++i) {
            int f = t + i*256;
            int ci = f / 9, r = f - ci*9;          // r = ky*3+kx
            float q = rintf(v[i] / s);
            q = fminf(fmaxf(q, -127.f), 127.f);
            w2t[(size_t)p*2304 + r*256 + ci] = f2bf(q);
        }
    } else if (bid < 1536) {               // ---- wq3
        int co = bid - 512;
        float v = w3[(size_t)co*256 + t];
        float m = blockReduceMax(fabsf(v));
        float s = fmaxf(m / 127.0f, 1e-8f);
        if (t == 0) sw3[co] = s;
        float q = rintf(v / s);
        q = fminf(fmaxf(q, -127.f), 127.f);
        w3q[(size_t)co*256 + t] = f2bf(q);
    } else {                               // ---- split
        int sb = bid - 1536;
        int b = sb >> 4, cg = sb & 15;
        const float* xb = x + ((size_t)b*1024 + cg*64) * 196;
        for (int i = t; i < 3136; i += 256) {
            f32x4 v = *(const f32x4*)&xb[i*4];
            int g = i*4;
#pragma unroll
            for (int j = 0; j < 4; ++j) {
                int gg = g + j;
                tile[gg + gg/196] = v[j];        // ch*197 + pos
            }
        }
        __syncthreads();
        for (int i = t; i < 3136; i += 256) {
            int pos = i >> 4, c4 = (i & 15) << 2;
            us4 hi, lo;
#pragma unroll
            for (int j = 0; j < 4; ++j) {
                float v = tile[(c4 + j)*197 + pos];
                u16 h = f2bf(v);
                hi[j] = h;
                lo[j] = f2bf(v - bf2f(h));
            }
            size_t n = (size_t)(b*196 + pos);
            *(us4*)&xsplit[n*2048 + cg*64 + c4]        = hi;
            *(us4*)&xsplit[n*2048 + 1024 + cg*64 + c4] = lo;
        }
    }
}

__global__ void k_coef(const float* g1, const float* b1, const float* m1, const float* v1,
                       const float* g2, const float* b2, const float* m2, const float* v2,
                       const float* g3, const float* b3, const float* m3, const float* v3,
                       const float* s1p, const float* s2p,
                       const float* sw1, const float* sw2, const float* sw3,
                       float* a1, float* c1, float* a2, float* c2, float* a3, float* c3) {
    int t = threadIdx.x;   // 1024 threads
    float s1 = fmaxf(s1p[0], 1e-6f), s2 = fmaxf(s2p[0], 1e-6f);
    if (t < 256) {
        float inv1 = g1[t] / sqrtf(v1[t] + 1e-5f);
        a1[t] = sw1[t] * inv1 / s1;
        c1[t] = (b1[t] - m1[t] * inv1) / s1;
        float inv2 = g2[t] / sqrtf(v2[t] + 1e-5f);
        a2[t] = sw2[t] * s1 * inv2 / s2;
        c2[t] = (b2[t] - m2[t] * inv2) / s2;
    }
    float inv3 = g3[t] / sqrtf(v3[t] + 1e-5f);
    a3[t] = sw3[t] * s2 * inv3;
    c3[t] = b3[t] - m3[t] * inv3;
}

// ---------------- the GEMM template ----------------
// C[m][n] = sum_k A[m][k] * B[n][k], BM=128, BN=64, BK=64, 4 waves (2Mx2N)
// 3-buffer LDS, 2-deep prefetch, counted vmcnt (6 GLL per stage per wave).
// CONV=1: A=w1d[256][2048],   B=xsplit[12544][2048] -> act1 (padded rows)
// CONV=2: A=w2t[256][2304],   B=act1[NPAD][256] (+row shift) -> act2 (real rows)
// CONV=3: A=act2[12544][256], B=w3q[1024][256] -> out (+identity, final qrelu)
template<int CONV>
__global__ __launch_bounds__(256) void k_gemm(
    const u16* __restrict__ A, const u16* __restrict__ Bact,
    u16* __restrict__ actout,
    const float* __restrict__ ca, const float* __restrict__ cc,
    const float* __restrict__ xin, const float* __restrict__ s3p,
    float* __restrict__ outp)
{
    constexpr int KSA = CONV==1 ? 2048 : (CONV==2 ? 2304 : 256);
    constexpr int KSB = CONV==1 ? 2048 : 256;
    constexpr int NKT = CONV==1 ? 32 : (CONV==2 ? 36 : 4);

    __shared__ u16 lA[3][128*64];
    __shared__ u16 lB[3][64*64];

    const int t = threadIdx.x;
    const int lane = t & 63, wv = t >> 6;
    const int n0 = blockIdx.x * 64, m0 = blockIdx.y * 128;

    f32x4 acc[4][2];
#pragma unroll
    for (int i = 0; i < 4; ++i)
#pragma unroll
        for (int j = 0; j < 2; ++j) acc[i][j] = f32x4{0.f,0.f,0.f,0.f};

    const int srA = wv*32 + (lane >> 3);                     // A staging row (+c*8)
    const int srB = wv*16 + (lane >> 3);                     // B staging row (+c*8)
    const int ssel = (((lane & 7) ^ ((lane >> 3) & 7))) * 8; // swizzle-inverted src col (elems)
    const int wr = wv >> 1, wc = wv & 1;
    const int fr = lane & 15, fg = lane >> 4;
    const int fsw = (fr & 7) << 4;                           // ds_read XOR (bytes)

    // stage tile kt into buffer buf (6 GLL per wave)
    auto stageK = [&](int kt, int buf) {
        int bcol, bshift;
        if constexpr (CONV == 2) {
            bcol = (kt & 3) * 64;
            int kpos = kt >> 2;
            int ky = kpos / 3, kx = kpos - ky*3;
            bshift = (ky - 1)*16 + (kx - 1);
        } else { bcol = kt * 64; bshift = 0; }
#pragma unroll
        for (int c = 0; c < 4; ++c) {
            const u16* g = A + (size_t)(m0 + srA + c*8) * KSA + kt*64 + ssel;
            GLL(g, &lA[buf][(wv*32 + c*8) * 64]);
        }
#pragma unroll
        for (int c = 0; c < 2; ++c) {
            const u16* g = Bact + (ptrdiff_t)(n0 + srB + c*8 + bshift) * KSB + bcol + ssel;
            GLL(g, &lB[buf][(wv*16 + c*8) * 64]);
        }
    };

    auto computeK = [&](int buf) {
        const char* bA = (const char*)&lA[buf][0];
        const char* bB = (const char*)&lB[buf][0];
        __builtin_amdgcn_s_setprio(1);
#pragma unroll
        for (int kk = 0; kk < 2; ++kk) {
            bf16x8 af[4], bfv[2];
#pragma unroll
            for (int m = 0; m < 4; ++m) {
                int row = wr*64 + m*16 + fr;
                const char* p = bA + row*128 + ((kk*64 + fg*16) ^ fsw);
                af[m] = __builtin_bit_cast(bf16x8, *(const us8*)p);
            }
#pragma unroll
            for (int n = 0; n < 2; ++n) {
                int row = wc*32 + n*16 + fr;
                const char* p = bB + row*128 + ((kk*64 + fg*16) ^ fsw);
                bfv[n] = __builtin_bit_cast(bf16x8, *(const us8*)p);
            }
#pragma unroll
            for (int m = 0; m < 4; ++m)
#pragma unroll
                for (int n = 0; n < 2; ++n)
                    acc[m][n] = __builtin_amdgcn_mfma_f32_16x16x32_bf16(af[m], bfv[n], acc[m][n], 0, 0, 0);
        }
        __builtin_amdgcn_s_setprio(0);
    };

    // prologue: 2 tiles in flight
    stageK(0, 0);
    stageK(1, 1);
    asm volatile("s_waitcnt vmcnt(6)" ::: "memory");  // tile 0 landed
    __builtin_amdgcn_s_barrier();

    int cur = 0;
    for (int kt = 0; kt < NKT; ++kt) {
        int nxt2 = cur + 2; if (nxt2 >= 3) nxt2 -= 3;
        if (kt + 2 < NKT) stageK(kt + 2, nxt2);
        computeK(cur);
        if (kt + 1 < NKT) {
            if (kt + 2 < NKT) { asm volatile("s_waitcnt vmcnt(6)" ::: "memory"); }
            else              { asm volatile("s_waitcnt vmcnt(0)" ::: "memory"); }
            __builtin_amdgcn_s_barrier();
        }
        cur = cur + 1 == 3 ? 0 : cur + 1;
    }

    // epilogue. C/D layout: col = lane&15 (n-side), row = fg*4 + j (+16m) (m-side)
    const int pb = m0 + wr*64 + fg*4;
    const int nb = n0 + wc*32 + fr;

    if constexpr (CONV != 3) {
        (void)xin; (void)s3p; (void)outp;
#pragma unroll
        for (int m = 0; m < 4; ++m) {
            int p0 = pb + m*16;
            float av[4], cv[4];
#pragma unroll
            for (int j = 0; j < 4; ++j) { av[j] = ca[p0+j]; cv[j] = cc[p0+j]; }
#pragma unroll
            for (int n = 0; n < 2; ++n) {
                int nn = nb + n*16;
                int np;
                if constexpr (CONV == 1) {     // real n -> padded row (always interior)
                    int b  = nn / 196;
                    int pos = nn - b*196;
                    int h = pos / 14, w = pos - h*14;
                    np = b*256 + (h+1)*16 + (w+1);
                } else {                       // padded n -> real row; skip ring
                    int hp = (nn >> 4) & 15, wp = nn & 15;
                    if (hp < 1 || hp > 14 || wp < 1 || wp > 14) continue;
                    np = (nn >> 8)*196 + (hp-1)*14 + (wp-1);
                }
                us4 st;
#pragma unroll
                for (int j = 0; j < 4; ++j) {
                    float y = fmaxf(acc[m][n][j]*av[j] + cv[j], 0.f);
                    float q = fminf(rintf(y), 255.f);
                    st[j] = f2bf(q);
                }
                *(us4*)&actout[(size_t)np*256 + p0] = st;
            }
        }
    } else {
        (void)actout;
        float s3 = fmaxf(s3p[0], 1e-6f);
        float rs3 = 1.0f / s3;
#pragma unroll
        for (int n = 0; n < 2; ++n) {
            int co = nb + n*16;
            float av = ca[co], cv = cc[co];
#pragma unroll
            for (int m = 0; m < 4; ++m) {
                int p4 = pb + m*16;            // 4 consecutive positions (never cross batch)
                int b  = p4 / 196;
                int hw = p4 - b*196;
                size_t off = ((size_t)((b << 10) + co))*196 + hw;
                f32x4 xv = *(const f32x4*)&xin[off];
                f32x4 st;
#pragma unroll
                for (int j = 0; j < 4; ++j) {
                    float y = fmaxf(acc[m][n][j]*av + cv + xv[j], 0.f);
                    float q = fminf(rintf(y * rs3), 255.f);
                    st[j] = q * s3;
                }
                *(f32x4*)&outp[off] = st;
            }
        }
    }
}

// ---------------- launch ----------------
extern "C" void kernel_launch(void* const* d_in, const int* in_sizes, int n_in,
                              void* d_out, int out_size, void* d_ws, size_t ws_size,
                              hipStream_t stream) {
    (void)in_sizes; (void)n_in; (void)out_size; (void)ws_size;
    const float* x   = (const float*)d_in[0];
    const float* w1  = (const float*)d_in[1];
    const float* w2  = (const float*)d_in[2];
    const float* w3  = (const float*)d_in[3];
    const float* g1  = (const float*)d_in[4];
    const float* b1  = (const float*)d_in[5];
    const float* m1  = (const float*)d_in[6];
    const float* v1  = (const float*)d_in[7];
    const float* g2  = (const float*)d_in[8];
    const float* b2  = (const float*)d_in[9];
    const float* m2  = (const float*)d_in[10];
    const float* v2  = (const float*)d_in[11];
    const float* g3  = (const float*)d_in[12];
    const float* b3  = (const float*)d_in[13];
    const float* m3  = (const float*)d_in[14];
    const float* v3  = (const float*)d_in[15];
    const float* s1p = (const float*)d_in[16];
    const float* s2p = (const float*)d_in[17];
    const float* s3p = (const float*)d_in[18];
    float* out = (float*)d_out;

    char* w = (char*)d_ws;
    u16* w1d = (u16*)w;  w += (size_t)256*2048*2;
    u16* w2t = (u16*)w;  w += (size_t)256*2304*2;
    u16* w3q = (u16*)w;  w += (size_t)1024*256*2;
    float* sw1 = (float*)w; w += 256*4;
    float* sw2 = (float*)w; w += 256*4;
    float* sw3 = (float*)w; w += 1024*4;
    float* a1 = (float*)w; w += 256*4;
    float* c1 = (float*)w; w += 256*4;
    float* a2 = (float*)w; w += 256*4;
    float* c2 = (float*)w; w += 256*4;
    float* a3 = (float*)w; w += 1024*4;
    float* c3 = (float*)w; w += 1024*4;
    u16* xsplit = (u16*)w; w += (size_t)NREAL*2048*2;
    u16* act1g  = (u16*)w; w += (size_t)(NPAD + 2*GUARD_ROWS)*256*2;
    u16* act1   = act1g + (size_t)GUARD_ROWS*256;
    u16* act2   = (u16*)w; w += (size_t)NREAL*256*2;

    // zero act1 incl. guards (conv2's zero-padding ring lives here)
    hipMemsetAsync(act1g, 0, (size_t)(NPAD + 2*GUARD_ROWS)*256*2, stream);

    k_prep<<<2560, 256, 0, stream>>>(w1, w2, w3, x, w1d, w2t, w3q, sw1, sw2, sw3, xsplit);
    k_coef<<<1, 1024, 0, stream>>>(g1,b1,m1,v1, g2,b2,m2,v2, g3,b3,m3,v3,
                                   s1p, s2p, sw1, sw2, sw3,
                                   a1,c1, a2,c2, a3,c3);

    k_gemm<1><<<dim3(196, 2), 256, 0, stream>>>(w1d, xsplit, act1, a1, c1, nullptr, nullptr, nullptr);
    k_gemm<2><<<dim3(256, 2), 256, 0, stream>>>(w2t, act1, act2, a2, c2, nullptr, nullptr, nullptr);
    k_gemm<3><<<dim3(16, 98), 256, 0, stream>>>(act2, w3q, nullptr, a3, c3, x, s3p, out);
}

// Round 7
// 203.800 us; speedup vs baseline: 1.2275x; 1.2275x over previous
//
#include <hip/hip_runtime.h>
#include <stdint.h>
#include <stddef.h>

typedef unsigned short u16;
typedef unsigned int   u32;
typedef signed char    s8;
typedef int   i32x4 __attribute__((ext_vector_type(4)));
typedef float f32x4 __attribute__((ext_vector_type(4)));
typedef s8    s8x4  __attribute__((ext_vector_type(4)));
typedef u32   u32x4 __attribute__((ext_vector_type(4)));

#define DEVFN static __device__ __forceinline__

// async 16B/lane global->LDS (wave-uniform LDS base, per-lane global addr)
#define GLL(g, l) __builtin_amdgcn_global_load_lds( \
    (__attribute__((address_space(1))) void*)(g),   \
    (__attribute__((address_space(3))) void*)(l), 16, 0, 0)

// ---------------- geometry ----------------
#define NREAL 12544          // 64 * 196 real positions
#define NPAD  16384          // 64 * 256 padded (16x16) positions
#define GUARD_ROWS 32        // guard rows around act1 (conv2 row shifts are +-17)
#define SXI 4096.0f          // x fixed-point scale (s_x = 1/4096)

// ---------------- block reductions (256 threads) ----------------
DEVFN float blockReduceMax(float m) {
    for (int off = 32; off; off >>= 1) m = fmaxf(m, __shfl_xor(m, off));
    __shared__ float s[4];
    int lane = threadIdx.x & 63, w = threadIdx.x >> 6;
    if (lane == 0) s[w] = m;
    __syncthreads();
    return fmaxf(fmaxf(s[0], s[1]), fmaxf(s[2], s[3]));
}
DEVFN float blockReduceSum(float v) {
    for (int off = 32; off; off >>= 1) v += __shfl_xor(v, off);
    __shared__ float s[4];
    int lane = threadIdx.x & 63, w = threadIdx.x >> 6;
    __syncthreads();
    if (lane == 0) s[w] = v;
    __syncthreads();
    return s[0] + s[1] + s[2] + s[3];
}

// ---------------- merged prep kernel ----------------
// bid 0..255    : wq1  w1[256][1024] -> w1q8[256][2048] (dup) + a1,c1
// bid 256..511  : wq2  w2[256][2304] -> w2t8[256][2304] (k=r*256+ci) + a2,c2
// bid 512..1535 : wq3  w3[1024][256] -> w3q8 + a3,c3
// bid 1536..2559: split x NCHW fp32 -> xq[12544][2048] s8 (hi|lo fixed-point)
// bid 2560..2819: fill act1g with 0x80 (== activation 0 after -128 offset)
__global__ __launch_bounds__(256) void k_prep(
    const float* __restrict__ w1, const float* __restrict__ w2, const float* __restrict__ w3,
    const float* __restrict__ x,
    const float* __restrict__ g1, const float* __restrict__ b1, const float* __restrict__ m1, const float* __restrict__ v1,
    const float* __restrict__ g2, const float* __restrict__ b2, const float* __restrict__ m2, const float* __restrict__ v2,
    const float* __restrict__ g3, const float* __restrict__ b3, const float* __restrict__ m3, const float* __restrict__ v3,
    const float* __restrict__ s1p, const float* __restrict__ s2p,
    s8* __restrict__ w1q8, s8* __restrict__ w2t8, s8* __restrict__ w3q8,
    float* __restrict__ a1, float* __restrict__ c1,
    float* __restrict__ a2, float* __restrict__ c2,
    float* __restrict__ a3, float* __restrict__ c3,
    s8* __restrict__ xq, s8* __restrict__ act1g)
{
    __shared__ float tile[64*197];
    const int bid = blockIdx.x, t = threadIdx.x;

    if (bid < 256) {                       // ---- wq1 + coef1
        int p = bid;
        const float* wr = w1 + (size_t)p * 1024;
        float v[4], mx = 0.f;
        for (int i = 0; i < 4; ++i) { v[i] = wr[t + i*256]; mx = fmaxf(mx, fabsf(v[i])); }
        mx = blockReduceMax(mx);
        float s = fmaxf(mx / 127.0f, 1e-8f);
        float qs = 0.f;
        for (int i = 0; i < 4; ++i) {
            float q = fminf(fmaxf(rintf(v[i] / s), -127.f), 127.f);
            s8 qb = (s8)(int)q;
            w1q8[(size_t)p*2048 + t + i*256]        = qb;
            w1q8[(size_t)p*2048 + 1024 + t + i*256] = qb;
            qs += q;
        }
        qs = blockReduceSum(qs);
        if (t == 0) {
            float s1 = fmaxf(s1p[0], 1e-6f);
            float inv = g1[p] / sqrtf(v1[p] + 1e-5f);
            float a = s * (1.0f / SXI) * inv / s1;
            a1[p] = a;
            c1[p] = (b1[p] - m1[p] * inv) / s1 + 128.0f * qs * a;
        }
    } else if (bid < 512) {                // ---- wq2 + coef2
        int p = bid - 256;
        const float* wr = w2 + (size_t)p * 2304;
        float v[9], mx = 0.f;
        for (int i = 0; i < 9; ++i) { v[i] = wr[t + i*256]; mx = fmaxf(mx, fabsf(v[i])); }
        mx = blockReduceMax(mx);
        float s = fmaxf(mx / 127.0f, 1e-8f);
        float qs = 0.f;
        for (int i = 0; i < 9; ++i) {
            int f = t + i*256;
            int ci = f / 9, r = f - ci*9;          // r = ky*3+kx
            float q = fminf(fmaxf(rintf(v[i] / s), -127.f), 127.f);
            w2t8[(size_t)p*2304 + r*256 + ci] = (s8)(int)q;
            qs += q;
        }
        qs = blockReduceSum(qs);
        if (t == 0) {
            float s1 = fmaxf(s1p[0], 1e-6f), s2 = fmaxf(s2p[0], 1e-6f);
            float inv = g2[p] / sqrtf(v2[p] + 1e-5f);
            float a = s * s1 * inv / s2;
            a2[p] = a;
            c2[p] = (b2[p] - m2[p] * inv) / s2 + 128.0f * qs * a;
        }
    } else if (bid < 1536) {               // ---- wq3 + coef3
        int co = bid - 512;
        float v = w3[(size_t)co*256 + t];
        float mx = blockReduceMax(fabsf(v));
        float s = fmaxf(mx / 127.0f, 1e-8f);
        float q = fminf(fmaxf(rintf(v / s), -127.f), 127.f);
        w3q8[(size_t)co*256 + t] = (s8)(int)q;
        float qs = blockReduceSum(q);
        if (t == 0) {
            float s2 = fmaxf(s2p[0], 1e-6f);
            float inv = g3[co] / sqrtf(v3[co] + 1e-5f);
            float a = s * s2 * inv;
            a3[co] = a;
            c3[co] = (b3[co] - m3[co] * inv) + 128.0f * qs * a;
        }
    } else if (bid < 2560) {               // ---- split x -> fixed-point hi/lo
        int sb = bid - 1536;
        int b = sb >> 4, cg = sb & 15;
        const float* xb = x + ((size_t)b*1024 + cg*64) * 196;
        for (int i = t; i < 3136; i += 256) {
            f32x4 v = *(const f32x4*)&xb[i*4];
            int g = i*4;
#pragma unroll
            for (int j = 0; j < 4; ++j) {
                int gg = g + j;
                tile[gg + gg/196] = v[j];        // ch*197 + pos
            }
        }
        __syncthreads();
        for (int i = t; i < 3136; i += 256) {
            int pos = i >> 4, c4 = (i & 15) << 2;
            s8x4 hi, lo;
#pragma unroll
            for (int j = 0; j < 4; ++j) {
                float v = tile[(c4 + j)*197 + pos];
                int xf = (int)rintf(v * SXI);
                xf = xf > 32767 ? 32767 : (xf < -32767 ? -32767 : xf);
                int h = xf >> 8;                 // arithmetic
                int l = xf - (h << 8) - 128;     // in [-128,127]
                hi[j] = (s8)h;
                lo[j] = (s8)l;
            }
            size_t n = (size_t)(b*196 + pos);
            *(s8x4*)&xq[n*2048 + cg*64 + c4]        = hi;
            *(s8x4*)&xq[n*2048 + 1024 + cg*64 + c4] = lo;
        }
    } else {                               // ---- fill act1g with 0x80
        const int total16 = (NPAD + 2*GUARD_ROWS) * 256 / 16;
        u32x4 val; val[0] = val[1] = val[2] = val[3] = 0x80808080u;
        u32x4* dst = (u32x4*)act1g;
        for (int i = (bid - 2560)*256 + t; i < total16; i += 260*256) dst[i] = val;
    }
}

// ---------------- the i8 GEMM template ----------------
// C[m][n] = sum_k A[m][k]*B[n][k], BM=128, BN=64, BK=128 bytes, 4 waves (2Mx2N)
// 3-buffer LDS, 2-deep prefetch, counted vmcnt (6 GLL per stage per wave), i8 MFMA.
// CONV=1: A=w1q8[256][2048],  B=xq[12544][2048] -> act1 s8 (padded rows); dual acc (hi/lo planes)
// CONV=2: A=w2t8[256][2304],  B=act1[NPAD][256] (+row shift) -> act2 s8 (real rows)
// CONV=3: A=act2[12544][256], B=w3q8[1024][256] -> out fp32 (+identity, final qrelu)
template<int CONV>
__global__ __launch_bounds__(256) void k_gemm(
    const s8* __restrict__ A, const s8* __restrict__ Bact,
    s8* __restrict__ actout,
    const float* __restrict__ ca, const float* __restrict__ cc,
    const float* __restrict__ xin, const float* __restrict__ s3p,
    float* __restrict__ outp)
{
    constexpr int KSA = CONV==1 ? 2048 : (CONV==2 ? 2304 : 256);
    constexpr int KSB = CONV==1 ? 2048 : 256;
    constexpr int NKT = CONV==1 ? 16 : (CONV==2 ? 18 : 2);

    __shared__ s8 lA[3][128*128];
    __shared__ s8 lB[3][64*128];

    const int t = threadIdx.x;
    const int lane = t & 63, wv = t >> 6;
    const int n0 = blockIdx.x * 64, m0 = blockIdx.y * 128;

    i32x4 acc[4][2], accB[4][2];
#pragma unroll
    for (int i = 0; i < 4; ++i)
#pragma unroll
        for (int j = 0; j < 2; ++j) { acc[i][j] = i32x4{0,0,0,0}; accB[i][j] = i32x4{0,0,0,0}; }

    const int srA = wv*32 + (lane >> 3);                      // A staging row (+c*8)
    const int srB = wv*16 + (lane >> 3);                      // B staging row (+c*8)
    const int ssel = (((lane & 7) ^ ((lane >> 3) & 7))) * 16; // swizzle-inverted src col (bytes)
    const int wr = wv >> 1, wc = wv & 1;
    const int fr = lane & 15, fg = lane >> 4;
    const int fsw = (fr & 7) << 4;                            // ds_read XOR (bytes)

    auto stageK = [&](int kt, int buf) {
        int bcol, bshift;
        if constexpr (CONV == 2) {
            bcol = (kt & 1) * 128;
            int kpos = kt >> 1;
            int ky = kpos / 3, kx = kpos - ky*3;
            bshift = (ky - 1)*16 + (kx - 1);
        } else { bcol = kt * 128; bshift = 0; }
#pragma unroll
        for (int c = 0; c < 4; ++c) {
            const s8* g = A + (size_t)(m0 + srA + c*8) * KSA + kt*128 + ssel;
            GLL(g, &lA[buf][(wv*32 + c*8) * 128]);
        }
#pragma unroll
        for (int c = 0; c < 2; ++c) {
            const s8* g = Bact + (ptrdiff_t)(n0 + srB + c*8 + bshift) * KSB + bcol + ssel;
            GLL(g, &lB[buf][(wv*16 + c*8) * 128]);
        }
    };

    auto computeK = [&](int buf, i32x4 (&ac)[4][2]) {
        const s8* bA = &lA[buf][0];
        const s8* bB = &lB[buf][0];
        __builtin_amdgcn_s_setprio(1);
#pragma unroll
        for (int kk = 0; kk < 2; ++kk) {
            i32x4 af[4], bf[2];
#pragma unroll
            for (int m = 0; m < 4; ++m) {
                int row = wr*64 + m*16 + fr;
                af[m] = *(const i32x4*)(bA + row*128 + ((kk*64 + fg*16) ^ fsw));
            }
#pragma unroll
            for (int n = 0; n < 2; ++n) {
                int row = wc*32 + n*16 + fr;
                bf[n] = *(const i32x4*)(bB + row*128 + ((kk*64 + fg*16) ^ fsw));
            }
#pragma unroll
            for (int m = 0; m < 4; ++m)
#pragma unroll
                for (int n = 0; n < 2; ++n)
                    ac[m][n] = __builtin_amdgcn_mfma_i32_16x16x64_i8(af[m], bf[n], ac[m][n], 0, 0, 0);
        }
        __builtin_amdgcn_s_setprio(0);
    };

    // prologue: 2 tiles in flight
    stageK(0, 0);
    stageK(1, 1);
    asm volatile("s_waitcnt vmcnt(6)" ::: "memory");  // tile 0 landed
    __builtin_amdgcn_s_barrier();

#pragma unroll
    for (int kt = 0; kt < NKT; ++kt) {
        const int buf = kt % 3;
        if (kt + 2 < NKT) stageK(kt + 2, (kt + 2) % 3);
        if (CONV == 1 && kt >= 8) computeK(buf, accB);   // lo plane
        else                      computeK(buf, acc);    // hi plane / only plane
        if (kt + 1 < NKT) {
            if (kt + 2 < NKT) { asm volatile("s_waitcnt vmcnt(6)" ::: "memory"); }
            else              { asm volatile("s_waitcnt vmcnt(0)" ::: "memory"); }
            __builtin_amdgcn_s_barrier();
        }
    }

    // epilogue. C/D layout: col = lane&15 (n-side), row = fg*4 + j (+16m) (m-side)
    const int pb = m0 + wr*64 + fg*4;
    const int nb = n0 + wc*32 + fr;

    if constexpr (CONV != 3) {
        (void)xin; (void)s3p; (void)outp;
#pragma unroll
        for (int m = 0; m < 4; ++m) {
            int p0 = pb + m*16;
            float av[4], cv[4];
#pragma unroll
            for (int j = 0; j < 4; ++j) { av[j] = ca[p0+j]; cv[j] = cc[p0+j]; }
#pragma unroll
            for (int n = 0; n < 2; ++n) {
                int nn = nb + n*16;
                int np;
                if constexpr (CONV == 1) {     // real n -> padded row (always interior)
                    int b  = nn / 196;
                    int pos = nn - b*196;
                    int h = pos / 14, w = pos - h*14;
                    np = b*256 + (h+1)*16 + (w+1);
                } else {                       // padded n -> real row; skip ring
                    int hp = (nn >> 4) & 15, wp = nn & 15;
                    if (hp < 1 || hp > 14 || wp < 1 || wp > 14) continue;
                    np = (nn >> 8)*196 + (hp-1)*14 + (wp-1);
                }
                s8x4 st;
#pragma unroll
                for (int j = 0; j < 4; ++j) {
                    float fa;
                    if constexpr (CONV == 1)
                        fa = 256.0f * (float)acc[m][n][j] + (float)accB[m][n][j];
                    else
                        fa = (float)acc[m][n][j];
                    float y = fmaxf(fa * av[j] + cv[j], 0.f);
                    int q = (int)fminf(rintf(y), 255.f);
                    st[j] = (s8)(q - 128);
                }
                *(s8x4*)&actout[(size_t)np*256 + p0] = st;
            }
        }
    } else {
        (void)actout;
        float s3 = fmaxf(s3p[0], 1e-6f);
        float rs3 = 1.0f / s3;
#pragma unroll
        for (int n = 0; n < 2; ++n) {
            int co = nb + n*16;
            float av = ca[co], cv = cc[co];
#pragma unroll
            for (int m = 0; m < 4; ++m) {
                int p4 = pb + m*16;            // 4 consecutive positions (never cross batch)
                int b  = p4 / 196;
                int hw = p4 - b*196;
                size_t off = ((size_t)((b << 10) + co))*196 + hw;
                f32x4 xv = *(const f32x4*)&xin[off];
                f32x4 st;
#pragma unroll
                for (int j = 0; j < 4; ++j) {
                    float y = fmaxf((float)acc[m][n][j] * av + cv + xv[j], 0.f);
                    float q = fminf(rintf(y * rs3), 255.f);
                    st[j] = q * s3;
                }
                *(f32x4*)&outp[off] = st;
            }
        }
    }
}

// ---------------- launch ----------------
extern "C" void kernel_launch(void* const* d_in, const int* in_sizes, int n_in,
                              void* d_out, int out_size, void* d_ws, size_t ws_size,
                              hipStream_t stream) {
    (void)in_sizes; (void)n_in; (void)out_size; (void)ws_size;
    const float* x   = (const float*)d_in[0];
    const float* w1  = (const float*)d_in[1];
    const float* w2  = (const float*)d_in[2];
    const float* w3  = (const float*)d_in[3];
    const float* g1  = (const float*)d_in[4];
    const float* b1  = (const float*)d_in[5];
    const float* m1  = (const float*)d_in[6];
    const float* v1  = (const float*)d_in[7];
    const float* g2  = (const float*)d_in[8];
    const float* b2  = (const float*)d_in[9];
    const float* m2  = (const float*)d_in[10];
    const float* v2  = (const float*)d_in[11];
    const float* g3  = (const float*)d_in[12];
    const float* b3  = (const float*)d_in[13];
    const float* m3  = (const float*)d_in[14];
    const float* v3  = (const float*)d_in[15];
    const float* s1p = (const float*)d_in[16];
    const float* s2p = (const float*)d_in[17];
    const float* s3p = (const float*)d_in[18];
    float* out = (float*)d_out;

    char* w = (char*)d_ws;
    s8* w1q8 = (s8*)w;  w += (size_t)256*2048;
    s8* w2t8 = (s8*)w;  w += (size_t)256*2304;
    s8* w3q8 = (s8*)w;  w += (size_t)1024*256;
    float* a1 = (float*)w; w += 256*4;
    float* c1 = (float*)w; w += 256*4;
    float* a2 = (float*)w; w += 256*4;
    float* c2 = (float*)w; w += 256*4;
    float* a3 = (float*)w; w += 1024*4;
    float* c3 = (float*)w; w += 1024*4;
    s8* xq    = (s8*)w; w += (size_t)NREAL*2048;
    s8* act1g = (s8*)w; w += (size_t)(NPAD + 2*GUARD_ROWS)*256;
    s8* act1  = act1g + (size_t)GUARD_ROWS*256;
    s8* act2  = (s8*)w; w += (size_t)NREAL*256;

    k_prep<<<2820, 256, 0, stream>>>(w1, w2, w3, x,
                                     g1,b1,m1,v1, g2,b2,m2,v2, g3,b3,m3,v3,
                                     s1p, s2p,
                                     w1q8, w2t8, w3q8,
                                     a1,c1, a2,c2, a3,c3,
                                     xq, act1g);

    k_gemm<1><<<dim3(196, 2), 256, 0, stream>>>(w1q8, xq, act1, a1, c1, nullptr, nullptr, nullptr);
    k_gemm<2><<<dim3(256, 2), 256, 0, stream>>>(w2t8, act1, act2, a2, c2, nullptr, nullptr, nullptr);
    k_gemm<3><<<dim3(16, 98), 256, 0, stream>>>(act2, w3q8, nullptr, a3, c3, x, s3p, out);
}